// Round 4
// baseline (104.481 us; speedup 1.0000x reference)
//
#include <hip/hip_runtime.h>
#include <math.h>

// Gaussians covariance, MI355X. cov = s^2 * I exactly (isotropic scales,
// R orthogonal) -> problem is the exact 3-NN search over N^2 pairs.
//
// R4 (vs R3 knn_partial ~40us, LDS-pipe-bound):
//  - R3 issued one ds_read_b128 per wave-j-step; broadcast reads still pay
//    ~12 cyc each in the per-CU LDS pipe -> 9216*12 = 110k cyc ~ 46us/CU.
//  - Fix: IPT=4 register blocking — each thread owns 4 i's, so one b128
//    j-read feeds 32 VALU ops. LDS pipe drops to ~11.5us, under the ~15us
//    VALU floor (8 instr/pair: 3 fma + add + 4-op sorted insert).
//  - Grid 12 i-tiles x 64 j-splits = 768 blocks x 256 thr = 3 blocks/CU.
//  - Diagonal-overlap blocks (72/768) keep top-4 (self-distance ~0 takes a
//    slot, dropped at merge); the rest keep top-3.
// NOTE: total dur_us includes ~44us of harness overhead (256MiB d_ws 0xAA
// poison fill runs inside the timed window) — not addressable from here.

#define N_PTS   12288
#define THREADS 256
#define IPT     4
#define ITILE   (THREADS * IPT)    // 1024 i's per block
#define NIT     (N_PTS / ITILE)    // 12 i-tiles
#define GSPLIT  64                 // j-splits
#define JCH     (N_PTS / GSPLIT)   // 192 j's per block

__device__ __forceinline__ void ins4(float d, float& a0, float& a1,
                                     float& a2, float& a3) {
    // insert d into sorted a0<=a1<=a2<=a3, keep 4 smallest (5 VALU)
    const float n0 = fminf(a0, d);
    const float n1 = __builtin_amdgcn_fmed3f(a0, a1, d);
    const float n2 = __builtin_amdgcn_fmed3f(a1, a2, d);
    const float n3 = fminf(a3, fmaxf(a2, d));
    a0 = n0; a1 = n1; a2 = n2; a3 = n3;
}

__device__ __forceinline__ void ins3(float d, float& a0, float& a1, float& a2) {
    // insert d into sorted a0<=a1<=a2, keep 3 smallest (4 VALU)
    const float n0 = fminf(a0, d);
    const float n1 = __builtin_amdgcn_fmed3f(a0, a1, d);
    const float n2 = fminf(a2, fmaxf(a1, d));
    a0 = n0; a1 = n1; a2 = n2;
}

__global__ __launch_bounds__(THREADS) void knn_partial(
    const float* __restrict__ pts, float4* __restrict__ ws4)
{
    __shared__ float4 sj[JCH];     // 3 KB: (x, y, z, 0.5*|p|^2) per j
    const int t  = threadIdx.x;
    const int it = blockIdx.x;     // i-tile 0..11
    const int g  = blockIdx.y;     // j-split 0..63

    if (t < JCH) {
        const int j = g * JCH + t;
        const float x = pts[3 * j + 0];
        const float y = pts[3 * j + 1];
        const float z = pts[3 * j + 2];
        sj[t] = make_float4(x, y, z, 0.5f * fmaf(z, z, fmaf(y, y, x * x)));
    }

    // this thread's 4 i's: stride-THREADS so ws writes stay coalesced
    float px[IPT], py[IPT], pz[IPT], qi[IPT];
    #pragma unroll
    for (int r = 0; r < IPT; ++r) {
        const int i = it * ITILE + r * THREADS + t;
        px[r] = pts[3 * i + 0];
        py[r] = pts[3 * i + 1];
        pz[r] = pts[3 * i + 2];
        // identical op order to staging -> self-distance cancels to ~1 ulp
        qi[r] = 0.5f * fmaf(pz[r], pz[r], fmaf(py[r], py[r], px[r] * px[r]));
    }
    __syncthreads();

    float a0[IPT], a1[IPT], a2[IPT], a3[IPT];
    #pragma unroll
    for (int r = 0; r < IPT; ++r) {
        a0[r] = INFINITY; a1[r] = INFINITY; a2[r] = INFINITY; a3[r] = INFINITY;
    }

    const bool diag = (g * JCH < (it + 1) * ITILE) && (it * ITILE < (g + 1) * JCH);

    if (diag) {
        #pragma unroll 2
        for (int k = 0; k < JCH; ++k) {
            const float4 J = sj[k];
            #pragma unroll
            for (int r = 0; r < IPT; ++r) {
                float acc = fmaf(-J.x, px[r], qi[r]);
                acc = fmaf(-J.y, py[r], acc);
                acc = fmaf(-J.z, pz[r], acc);
                ins4(acc + J.w, a0[r], a1[r], a2[r], a3[r]);  // half sq dist
            }
        }
    } else {
        #pragma unroll 2
        for (int k = 0; k < JCH; ++k) {
            const float4 J = sj[k];
            #pragma unroll
            for (int r = 0; r < IPT; ++r) {
                float acc = fmaf(-J.x, px[r], qi[r]);
                acc = fmaf(-J.y, py[r], acc);
                acc = fmaf(-J.z, pz[r], acc);
                ins3(acc + J.w, a0[r], a1[r], a2[r]);         // a3 stays INF
            }
        }
    }

    #pragma unroll
    for (int r = 0; r < IPT; ++r) {
        const int i = it * ITILE + r * THREADS + t;
        ws4[(size_t)g * N_PTS + i] = make_float4(a0[r], a1[r], a2[r], a3[r]);
    }
}

__global__ __launch_bounds__(256) void knn_merge(
    const float4* __restrict__ ws4, float* __restrict__ out)
{
    const int i = blockIdx.x * 256 + threadIdx.x;
    float b0 = INFINITY, b1 = INFINITY, b2 = INFINITY, b3 = INFINITY;
    for (int g = 0; g < GSPLIT; ++g) {
        const float4 v = ws4[(size_t)g * N_PTS + i];   // coalesced
        ins4(v.x, b0, b1, b2, b3);
        ins4(v.y, b0, b1, b2, b3);
        ins4(v.z, b0, b1, b2, b3);
        ins4(v.w, b0, b1, b2, b3);
    }
    // b0 ~ 0 is the diagonal; b1..b3 are the 3-NN half squared distances
    const float d0 = sqrtf(fmaxf(b1 + b1, 0.0f));
    const float d1 = sqrtf(fmaxf(b2 + b2, 0.0f));
    const float d2 = sqrtf(fmaxf(b3 + b3, 0.0f));
    float mean = fmaxf((d0 + d1 + d2) * (1.0f / 3.0f), 1e-5f);
    const float s  = 0.001f * mean;
    const float s2 = s * s;

    float* o = out + (size_t)i * 9;
    o[0] = s2;   o[1] = 0.0f; o[2] = 0.0f;
    o[3] = 0.0f; o[4] = s2;   o[5] = 0.0f;
    o[6] = 0.0f; o[7] = 0.0f; o[8] = s2;
}

extern "C" void kernel_launch(void* const* d_in, const int* in_sizes, int n_in,
                              void* d_out, int out_size, void* d_ws, size_t ws_size,
                              hipStream_t stream) {
    const float* pts = (const float*)d_in[0];   // (N, 3) float32
    // d_in[1] = quaternions: algebraically irrelevant (cov = s^2 * I)
    float4* ws4 = (float4*)d_ws;                // 64 * 12288 * 16B = 12.6 MB
    float*  out = (float*)d_out;                // (N, 3, 3) float32

    knn_partial<<<dim3(NIT, GSPLIT), dim3(THREADS), 0, stream>>>(pts, ws4);
    knn_merge<<<dim3(N_PTS / 256), dim3(256), 0, stream>>>(ws4, out);
}